// Round 13
// baseline (181.900 us; speedup 1.0000x reference)
//
#include <hip/hip_runtime.h>

// 3D trilinear grid_sample (border, align_corners=False) of (4,256,256,256) f32
// voxels at N points, + bias. Output (N,4) f32.
//
// R13 = R11's 2-pass radix binning + tile-and-stage sampling, with the tile
// re-shaped to cut stage halo: 15z x 15y x 64x tiles, staged 16x16x66 cols
// fp16 = 132 KB LDS (160 KB available; R6/R11 used only 128). Stage amp
// (16/15)^2*(66/64) = 1.17 vs (8/7)^2 = 1.31 -> 300 MB vs 359 MB. Tiles:
// 18*18*4 = 1296, bijective XCD chunking (1296 = 8*162) so y/x-neighbor
// tiles share halo rows in the same XCD L2. Points whose x-pair crosses a
// 64-col boundary (~1.2%) + any bin overflow -> direct f32 sample in binB
// (no point can be dropped). R12 lesson: no overlap restructuring -- every
// attempt (R7-R10, R12) lost to this simple schedule.

#define SIDE 256
#define CHAN_STRIDE ((size_t)SIDE * SIDE * SIDE)
#define ZR 15
#define YR 15
#define NSZ 18                      // z-stripes
#define NTYQ 18                     // y-tiles per stripe
#define NXQ 4                       // x-quarters
#define BINS_B (NTYQ * NXQ)         // 72 bins per stripe in pass B
#define NTILES (NSZ * BINS_B)       // 1296
#define TROWS 256                   // 16 z-planes x 16 y-rows staged
#define TCOLS 66                    // 64 + 2 halo cols
#define CNT_STRIDE 16               // ints -> 64 B per counter
#define PPT 8                       // points per thread in bin passes
#define SCAP 131072                 // stripe cap (max stripe mean ~121K)
#define TCAP 3072                   // tile cap (max tile mean ~1.9K)
#define BPS 64                      // pass-B blocks per stripe (64*2048=131072)

// ws layout
#define SCNT_OFF 0
#define TCNT_OFF 4096
#define CNT_REGION (4096 + NTILES * CNT_STRIDE * 4)   // 87040, zeroed per call
#define SRECS_OFF ((size_t)CNT_REGION)
#define SRECS_BYTES ((size_t)NSZ * SCAP * 16)         // 37.7 MB
#define TRECS_OFF (SRECS_OFF + SRECS_BYTES)
#define TRECS_BYTES ((size_t)NTILES * TCAP * 16)      // 63.7 MB
#define WS_NEED (TRECS_OFF + TRECS_BYTES)             // ~101.5 MB

typedef float f2_unal __attribute__((ext_vector_type(2), aligned(4)));
typedef _Float16 h8_lds __attribute__((ext_vector_type(8), aligned(8)));
typedef _Float16 h8_al  __attribute__((ext_vector_type(8), aligned(16)));

// ---------------- f32 global sampling (R1, proven) -------------------------
__device__ __forceinline__ float4 sample_one(
    float px, float py, float pz,
    const float* __restrict__ vox, float4 bias)
{
    float ix = fminf(fmaxf(fmaf(px, 128.0f, 127.5f), 0.0f), 255.0f);
    float iy = fminf(fmaxf(fmaf(py, 128.0f, 127.5f), 0.0f), 255.0f);
    float iz = fminf(fmaxf(fmaf(pz, 128.0f, 127.5f), 0.0f), 255.0f);
    float fx = floorf(ix), fy = floorf(iy), fz = floorf(iz);
    float wx = ix - fx, wy = iy - fy, wz = iz - fz;
    int x0 = (int)fx, y0 = (int)fy, z0 = (int)fz;
    int xb = min(x0, SIDE - 2);
    bool xhi = (x0 > xb);
    int y1 = min(y0 + 1, SIDE - 1);
    int z1 = min(z0 + 1, SIDE - 1);
    float ux = 1.0f - wx, uy = 1.0f - wy, uz = 1.0f - wz;
    float w00 = uz * uy, w01 = uz * wy, w10 = wz * uy, w11 = wz * wy;
    size_t b00 = ((size_t)(z0 * SIDE + y0)) * SIDE + xb;
    size_t b01 = ((size_t)(z0 * SIDE + y1)) * SIDE + xb;
    size_t b10 = ((size_t)(z1 * SIDE + y0)) * SIDE + xb;
    size_t b11 = ((size_t)(z1 * SIDE + y1)) * SIDE + xb;
    float r[4];
#pragma unroll
    for (int c = 0; c < 4; ++c) {
        const float* v = vox + (size_t)c * CHAN_STRIDE;
        f2_unal q00 = *(const f2_unal*)(v + b00);
        f2_unal q01 = *(const f2_unal*)(v + b01);
        f2_unal q10 = *(const f2_unal*)(v + b10);
        f2_unal q11 = *(const f2_unal*)(v + b11);
        float a00 = xhi ? q00.y : q00.x;
        float a01 = xhi ? q01.y : q01.x;
        float a10 = xhi ? q10.y : q10.x;
        float a11 = xhi ? q11.y : q11.x;
        r[c] = w00 * fmaf(a00, ux, q00.y * wx)
             + w01 * fmaf(a01, ux, q01.y * wx)
             + w10 * fmaf(a10, ux, q10.y * wx)
             + w11 * fmaf(a11, ux, q11.y * wx);
    }
    return make_float4(r[0] + bias.x, r[1] + bias.y, r[2] + bias.z, r[3] + bias.w);
}

// ---------------- pass A: bin by z-stripe (18), LDS reorder ---------------
__global__ __launch_bounds__(256) void binA_kernel(
    const float* __restrict__ pos, int n,
    int* __restrict__ scnt, uint4* __restrict__ srecs,
    const float* __restrict__ vox, const float* __restrict__ biasp,
    float4* __restrict__ out)
{
    __shared__ int hist[NSZ], pref[NSZ + 1], gbase[NSZ];
    __shared__ uint4 sbuf[256 * PPT];
    __shared__ short sbin[256 * PPT];
    int tid = threadIdx.x;
    if (tid < NSZ) hist[tid] = 0;
    __syncthreads();

    size_t start = ((size_t)blockIdx.x * 256 + tid) * PPT;
    float buf[3 * PPT];
    bool full = (start + PPT <= (size_t)n);
    if (full) {
        const float4* p4 = (const float4*)(pos + 3 * start);
#pragma unroll
        for (int k = 0; k < 3 * PPT / 4; ++k) ((float4*)buf)[k] = p4[k];
    } else {
#pragma unroll
        for (int k = 0; k < 3 * PPT; ++k) {
            size_t e = 3 * start + k;
            buf[k] = (e < 3 * (size_t)n) ? pos[e] : 0.0f;
        }
    }

    int bin[PPT], rank[PPT];
#pragma unroll
    for (int j = 0; j < PPT; ++j) {
        bin[j] = -1;
        if (start + j < (size_t)n) {
            float pz = buf[3 * j + 2];
            float izf = fminf(fmaxf(fmaf(pz, 128.0f, 127.5f), 0.0f), 255.0f);
            int zs = ((int)floorf(izf)) / ZR;
            bin[j] = zs;
            rank[j] = atomicAdd(&hist[zs], 1);
        }
    }
    __syncthreads();
    if (tid == 0) {
        int s = 0;
#pragma unroll
        for (int b = 0; b < NSZ; ++b) { pref[b] = s; s += hist[b]; }
        pref[NSZ] = s;
    }
    __syncthreads();
#pragma unroll
    for (int j = 0; j < PPT; ++j) {
        if (bin[j] < 0) continue;
        int slot = pref[bin[j]] + rank[j];
        uint4 r;
        r.x = __float_as_uint(buf[3 * j + 0]);
        r.y = __float_as_uint(buf[3 * j + 1]);
        r.z = __float_as_uint(buf[3 * j + 2]);
        r.w = (unsigned)(start + j);
        sbuf[slot] = r;
        sbin[slot] = (short)bin[j];
    }
    if (tid < NSZ) gbase[tid] = hist[tid] ? atomicAdd(&scnt[tid * CNT_STRIDE], hist[tid]) : 0;
    __syncthreads();

    int tot = pref[NSZ];
    float4 bias = *(const float4*)biasp;
    for (int k = tid; k < tot; k += 256) {
        int b = sbin[k];
        int dst = gbase[b] + (k - pref[b]);
        uint4 r = sbuf[k];
        if (dst < SCAP) {
            srecs[(size_t)b * SCAP + dst] = r;   // coalesced runs
        } else {
            out[r.w] = sample_one(__uint_as_float(r.x), __uint_as_float(r.y),
                                  __uint_as_float(r.z), vox, bias);
        }
    }
}

// ---------------- pass B: per stripe, bin by (y-tile, x-quarter) -----------
__global__ __launch_bounds__(256) void binB_kernel(
    const int* __restrict__ scnt, const uint4* __restrict__ srecs,
    int* __restrict__ tcnt, uint4* __restrict__ trecs,
    const float* __restrict__ vox, const float* __restrict__ biasp,
    float4* __restrict__ out)
{
    __shared__ int hist[BINS_B], pref[BINS_B + 1], gbase[BINS_B];
    __shared__ uint4 sbuf[256 * PPT];
    __shared__ short sbin[256 * PPT];
    int tid = threadIdx.x;
    int s = blockIdx.x / BPS, blk = blockIdx.x % BPS;
    int cnt = min(scnt[s * CNT_STRIDE], SCAP);
    int base = blk * 256 * PPT;
    if (tid < BINS_B) hist[tid] = 0;
    __syncthreads();

    float4 bias = *(const float4*)biasp;
    uint4 R[PPT];
    int bin[PPT], rank[PPT];
#pragma unroll
    for (int j = 0; j < PPT; ++j) {
        bin[j] = -1;
        int ridx = base + j * 256 + tid;         // coalesced
        if (ridx < cnt) {
            R[j] = srecs[(size_t)s * SCAP + ridx];
            float px = __uint_as_float(R[j].x);
            float py = __uint_as_float(R[j].y);
            float ixf = fminf(fmaxf(fmaf(px, 128.0f, 127.5f), 0.0f), 255.0f);
            float iyf = fminf(fmaxf(fmaf(py, 128.0f, 127.5f), 0.0f), 255.0f);
            int x0 = (int)floorf(ixf);
            int y0 = (int)floorf(iyf);
            int xb = min(x0, SIDE - 2);
            if ((xb & 63) == 63) {
                bin[j] = -2;   // x-pair crosses quarter boundary: direct
            } else {
                bin[j] = (y0 / YR) * NXQ + (xb >> 6);
                rank[j] = atomicAdd(&hist[bin[j]], 1);
            }
        }
    }
    __syncthreads();
    if (tid == 0) {
        int t = 0;
#pragma unroll
        for (int b = 0; b < BINS_B; ++b) { pref[b] = t; t += hist[b]; }
        pref[BINS_B] = t;
    }
    __syncthreads();
#pragma unroll
    for (int j = 0; j < PPT; ++j) {
        if (bin[j] == -2) {
            out[R[j].w] = sample_one(__uint_as_float(R[j].x), __uint_as_float(R[j].y),
                                     __uint_as_float(R[j].z), vox, bias);
            continue;
        }
        if (bin[j] < 0) continue;
        int slot = pref[bin[j]] + rank[j];
        sbuf[slot] = R[j];
        sbin[slot] = (short)bin[j];
    }
    if (tid < BINS_B)
        gbase[tid] = hist[tid]
            ? atomicAdd(&tcnt[(s * BINS_B + tid) * CNT_STRIDE], hist[tid]) : 0;
    __syncthreads();

    int tot = pref[BINS_B];
    for (int k = tid; k < tot; k += 256) {
        int b = sbin[k];
        int dst = gbase[b] + (k - pref[b]);
        uint4 r = sbuf[k];
        if (dst < TCAP) {
            trecs[(size_t)(s * BINS_B + b) * TCAP + dst] = r;
        } else {
            out[r.w] = sample_one(__uint_as_float(r.x), __uint_as_float(r.y),
                                  __uint_as_float(r.z), vox, bias);
        }
    }
}

// ---------------- sample pass: 132 KB fp16 tile, 1 tile per block ----------
__global__ __launch_bounds__(1024) void sample_tiles_kernel(
    const uint4* __restrict__ trecs, const int* __restrict__ tcnt,
    const float* __restrict__ vox, const float* __restrict__ biasp,
    float4* __restrict__ out)
{
    __shared__ _Float16 tile[TROWS * TCOLS * 4];  // 135,168 B

    float4 bias = *(const float4*)biasp;
    int tid = threadIdx.x;

    // bijective XCD chunking: 1296 = 8 * 162; neighbor tiles share halo in L2
    int t = (blockIdx.x & 7) * (NTILES / 8) + (blockIdx.x >> 3);

    int zt = t / BINS_B;
    int rem = t - zt * BINS_B;
    int yt = rem >> 2, xq = rem & 3;
    int zbase = zt * ZR, ybase = yt * YR, xbase = xq << 6;

    // ---- stage: 256 rows x 33 x-pairs, f32->fp16, coalesced ----
#pragma unroll
    for (int it = 0; it < 9; ++it) {
        int q = it * 1024 + tid;          // 0..8447
        if (q < TROWS * (TCOLS / 2)) {
            int row = q / (TCOLS / 2);    // 0..255  (16z x 16y)
            int p   = q - row * (TCOLS / 2);  // 0..32
            int zp = min(zbase + (row >> 4), SIDE - 1);
            int yp = min(ybase + (row & 15), SIDE - 1);
            int gx = min(xbase + 2 * p, SIDE - 2);
            size_t gbase = ((size_t)(zp * SIDE + yp)) * SIDE + gx;
            float2 f0 = *(const float2*)(vox + gbase);
            float2 f1 = *(const float2*)(vox + CHAN_STRIDE + gbase);
            float2 f2 = *(const float2*)(vox + 2 * CHAN_STRIDE + gbase);
            float2 f3 = *(const float2*)(vox + 3 * CHAN_STRIDE + gbase);
            h8_al o;
            o[0] = (_Float16)f0.x; o[1] = (_Float16)f1.x;
            o[2] = (_Float16)f2.x; o[3] = (_Float16)f3.x;
            o[4] = (_Float16)f0.y; o[5] = (_Float16)f1.y;
            o[6] = (_Float16)f2.y; o[7] = (_Float16)f3.y;
            *(h8_al*)(tile + ((size_t)row * TCOLS + 2 * p) * 4) = o;  // 16B-aligned
        }
    }
    __syncthreads();

    // ---- sample this tile's points from LDS ----
    int cnt = min(tcnt[t * CNT_STRIDE], TCAP);
    const uint4* rec = trecs + (size_t)t * TCAP;
    for (int r = tid; r < cnt; r += 1024) {
        uint4 R = rec[r];
        float px = __uint_as_float(R.x);
        float py = __uint_as_float(R.y);
        float pz = __uint_as_float(R.z);

        float ix = fminf(fmaxf(fmaf(px, 128.0f, 127.5f), 0.0f), 255.0f);
        float iy = fminf(fmaxf(fmaf(py, 128.0f, 127.5f), 0.0f), 255.0f);
        float iz = fminf(fmaxf(fmaf(pz, 128.0f, 127.5f), 0.0f), 255.0f);
        float fx = floorf(ix), fy = floorf(iy), fz = floorf(iz);
        float wx = ix - fx, wy = iy - fy, wz = iz - fz;
        int x0 = (int)fx, y0 = (int)fy, z0 = (int)fz;
        int xb = min(x0, SIDE - 2);
        bool xhi = (x0 > xb);
        int y1 = min(y0 + 1, SIDE - 1);
        int z1 = min(z0 + 1, SIDE - 1);

        int zl = z0 - zbase, zl1 = z1 - zbase;   // 0..15
        int yl = y0 - ybase, yl1 = y1 - ybase;   // 0..15
        int xloc = xb - xbase;                   // 0..62

        int r00 = (zl  << 4) + yl,  r01 = (zl  << 4) + yl1;
        int r10 = (zl1 << 4) + yl,  r11 = (zl1 << 4) + yl1;

        float ux = 1.0f - wx, uy = 1.0f - wy, uz = 1.0f - wz;
        float w00 = uz * uy, w01 = uz * wy, w10 = wz * uy, w11 = wz * wy;

        h8_lds v00 = *(const h8_lds*)(tile + (r00 * TCOLS + xloc) * 4);
        h8_lds v01 = *(const h8_lds*)(tile + (r01 * TCOLS + xloc) * 4);
        h8_lds v10 = *(const h8_lds*)(tile + (r10 * TCOLS + xloc) * 4);
        h8_lds v11 = *(const h8_lds*)(tile + (r11 * TCOLS + xloc) * 4);

        float acc[4];
#pragma unroll
        for (int c = 0; c < 4; ++c) {
            float lo00 = (float)(xhi ? v00[4 + c] : v00[c]);
            float lo01 = (float)(xhi ? v01[4 + c] : v01[c]);
            float lo10 = (float)(xhi ? v10[4 + c] : v10[c]);
            float lo11 = (float)(xhi ? v11[4 + c] : v11[c]);
            float hi00 = (float)v00[4 + c];
            float hi01 = (float)v01[4 + c];
            float hi10 = (float)v10[4 + c];
            float hi11 = (float)v11[4 + c];
            acc[c] = w00 * fmaf(lo00, ux, hi00 * wx)
                   + w01 * fmaf(lo01, ux, hi01 * wx)
                   + w10 * fmaf(lo10, ux, hi10 * wx)
                   + w11 * fmaf(lo11, ux, hi11 * wx);
        }
        out[R.w] = make_float4(acc[0] + bias.x, acc[1] + bias.y,
                               acc[2] + bias.z, acc[3] + bias.w);
    }
}

// ---------------- fallback: direct (R1, 636 us) ----------------------------
__global__ __launch_bounds__(256) void vox_trilerp_kernel(
    const float* __restrict__ pos, const float* __restrict__ vox,
    const float* __restrict__ biasp, float* __restrict__ out, int n)
{
    int i = blockIdx.x * blockDim.x + threadIdx.x;
    if (i >= n) return;
    float4 bias = *(const float4*)biasp;
    float4 res = sample_one(pos[3 * (size_t)i], pos[3 * (size_t)i + 1],
                            pos[3 * (size_t)i + 2], vox, bias);
    *(float4*)(out + 4 * (size_t)i) = res;
}

extern "C" void kernel_launch(void* const* d_in, const int* in_sizes, int n_in,
                              void* d_out, int out_size, void* d_ws, size_t ws_size,
                              hipStream_t stream) {
    const float* pos  = (const float*)d_in[0];
    const float* vox  = (const float*)d_in[1];
    const float* bias = (const float*)d_in[2];
    float* out = (float*)d_out;

    int n = in_sizes[0] / 3;

    if (ws_size >= WS_NEED && n >= 256 * PPT) {
        int* scnt    = (int*)((char*)d_ws + SCNT_OFF);
        int* tcnt    = (int*)((char*)d_ws + TCNT_OFF);
        uint4* srecs = (uint4*)((char*)d_ws + SRECS_OFF);
        uint4* trecs = (uint4*)((char*)d_ws + TRECS_OFF);
        hipMemsetAsync(d_ws, 0, CNT_REGION, stream);
        int grid1 = (n + 256 * PPT - 1) / (256 * PPT);
        binA_kernel<<<grid1, 256, 0, stream>>>(pos, n, scnt, srecs, vox, bias,
                                               (float4*)out);
        binB_kernel<<<NSZ * BPS, 256, 0, stream>>>(scnt, srecs, tcnt, trecs,
                                                   vox, bias, (float4*)out);
        sample_tiles_kernel<<<NTILES, 1024, 0, stream>>>(trecs, tcnt, vox, bias,
                                                         (float4*)out);
    } else {
        int grid = (n + 255) / 256;
        vox_trilerp_kernel<<<grid, 256, 0, stream>>>(pos, vox, bias, out, n);
    }
}

// Round 14
// 149.150 us; speedup vs baseline: 1.2196x; 1.2196x over previous
//
#include <hip/hip_runtime.h>

// 3D trilinear grid_sample (border, align_corners=False) of (4,256,256,256) f32
// voxels at N points, + bias. Output (N,4) f32.
//
// R14 = R11 verbatim (best: 149.5 us). 2-pass LDS-reorder radix binning
// (coalesced record writes) + tile-and-stage sampling (8z x 8y x 256x fp16
// 128 KB LDS tile per block). Reverted after R12 (T14 reg-prefetch, 160) and
// R13 (132 KB big-tile, 182) both regressed; the ledger over R7-R13 shows
// every overlap/geometry restructuring loses to this simple schedule:
//   R7 512thr+2blk/CU: 189 | R8/R9 explicit dbuf: 231 | R10 phase-lock: 193
//   R12 T14: 160 | R13 big tile: 182 | R11: 149.5  <-- this kernel
// Overflow at any level -> direct f32 sample (no point can be dropped).

#define SIDE 256
#define CHAN_STRIDE ((size_t)SIDE * SIDE * SIDE)
#define ZR 7
#define YR 7
#define NS 37                       // z-stripes
#define NTY 37                      // y-tiles per stripe
#define NTILES (NS * NTY)           // 1369
#define CNT_STRIDE 16               // ints -> 64 B per counter
#define PPT 8                       // points per thread in bin passes
#define SCAP 65536                  // stripe cap (border mean 58.6K, +29 sigma)
#define TCAP 3072                   // tile cap (border mean ~1740, +33 sigma)
#define BPS 32                      // pass-B blocks per stripe (32*2048 = 65536)

// ws layout
#define SCNT_OFF 0
#define TCNT_OFF 4096
#define CNT_REGION 98304            // scnt + tcnt, zeroed each call
#define SRECS_OFF CNT_REGION
#define SRECS_BYTES ((size_t)NS * SCAP * 16)
#define TRECS_OFF (SRECS_OFF + SRECS_BYTES)
#define TRECS_BYTES ((size_t)NTILES * TCAP * 16)
#define WS_NEED (TRECS_OFF + TRECS_BYTES)   // ~106 MB

typedef float f2_unal __attribute__((ext_vector_type(2), aligned(4)));
typedef _Float16 h8_lds __attribute__((ext_vector_type(8), aligned(8)));
typedef _Float16 h8_al  __attribute__((ext_vector_type(8), aligned(16)));

// ---------------- f32 global sampling (R1, proven) -------------------------
__device__ __forceinline__ float4 sample_one(
    float px, float py, float pz,
    const float* __restrict__ vox, float4 bias)
{
    float ix = fminf(fmaxf(fmaf(px, 128.0f, 127.5f), 0.0f), 255.0f);
    float iy = fminf(fmaxf(fmaf(py, 128.0f, 127.5f), 0.0f), 255.0f);
    float iz = fminf(fmaxf(fmaf(pz, 128.0f, 127.5f), 0.0f), 255.0f);
    float fx = floorf(ix), fy = floorf(iy), fz = floorf(iz);
    float wx = ix - fx, wy = iy - fy, wz = iz - fz;
    int x0 = (int)fx, y0 = (int)fy, z0 = (int)fz;
    int xb = min(x0, SIDE - 2);
    bool xhi = (x0 > xb);
    int y1 = min(y0 + 1, SIDE - 1);
    int z1 = min(z0 + 1, SIDE - 1);
    float ux = 1.0f - wx, uy = 1.0f - wy, uz = 1.0f - wz;
    float w00 = uz * uy, w01 = uz * wy, w10 = wz * uy, w11 = wz * wy;
    size_t b00 = ((size_t)(z0 * SIDE + y0)) * SIDE + xb;
    size_t b01 = ((size_t)(z0 * SIDE + y1)) * SIDE + xb;
    size_t b10 = ((size_t)(z1 * SIDE + y0)) * SIDE + xb;
    size_t b11 = ((size_t)(z1 * SIDE + y1)) * SIDE + xb;
    float r[4];
#pragma unroll
    for (int c = 0; c < 4; ++c) {
        const float* v = vox + (size_t)c * CHAN_STRIDE;
        f2_unal q00 = *(const f2_unal*)(v + b00);
        f2_unal q01 = *(const f2_unal*)(v + b01);
        f2_unal q10 = *(const f2_unal*)(v + b10);
        f2_unal q11 = *(const f2_unal*)(v + b11);
        float a00 = xhi ? q00.y : q00.x;
        float a01 = xhi ? q01.y : q01.x;
        float a10 = xhi ? q10.y : q10.x;
        float a11 = xhi ? q11.y : q11.x;
        r[c] = w00 * fmaf(a00, ux, q00.y * wx)
             + w01 * fmaf(a01, ux, q01.y * wx)
             + w10 * fmaf(a10, ux, q10.y * wx)
             + w11 * fmaf(a11, ux, q11.y * wx);
    }
    return make_float4(r[0] + bias.x, r[1] + bias.y, r[2] + bias.z, r[3] + bias.w);
}

// ---------------- pass A: bin by z-stripe, LDS reorder, coalesced write ----
__global__ __launch_bounds__(256) void binA_kernel(
    const float* __restrict__ pos, int n,
    int* __restrict__ scnt, uint4* __restrict__ srecs,
    const float* __restrict__ vox, const float* __restrict__ biasp,
    float4* __restrict__ out)
{
    __shared__ int hist[NS], pref[NS + 1], gbase[NS];
    __shared__ uint4 sbuf[256 * PPT];
    __shared__ short sbin[256 * PPT];
    int tid = threadIdx.x;
    if (tid < NS) hist[tid] = 0;
    __syncthreads();

    size_t start = ((size_t)blockIdx.x * 256 + tid) * PPT;
    float buf[3 * PPT];
    bool full = (start + PPT <= (size_t)n);
    if (full) {
        const float4* p4 = (const float4*)(pos + 3 * start);
#pragma unroll
        for (int k = 0; k < 3 * PPT / 4; ++k) ((float4*)buf)[k] = p4[k];
    } else {
#pragma unroll
        for (int k = 0; k < 3 * PPT; ++k) {
            size_t e = 3 * start + k;
            buf[k] = (e < 3 * (size_t)n) ? pos[e] : 0.0f;
        }
    }

    int bin[PPT], rank[PPT];
#pragma unroll
    for (int j = 0; j < PPT; ++j) {
        bin[j] = -1;
        if (start + j < (size_t)n) {
            float pz = buf[3 * j + 2];
            float izf = fminf(fmaxf(fmaf(pz, 128.0f, 127.5f), 0.0f), 255.0f);
            int zs = ((int)floorf(izf)) / ZR;
            bin[j] = zs;
            rank[j] = atomicAdd(&hist[zs], 1);
        }
    }
    __syncthreads();
    if (tid == 0) {
        int s = 0;
#pragma unroll
        for (int b = 0; b < NS; ++b) { pref[b] = s; s += hist[b]; }
        pref[NS] = s;
    }
    __syncthreads();
#pragma unroll
    for (int j = 0; j < PPT; ++j) {
        if (bin[j] < 0) continue;
        int slot = pref[bin[j]] + rank[j];
        uint4 r;
        r.x = __float_as_uint(buf[3 * j + 0]);
        r.y = __float_as_uint(buf[3 * j + 1]);
        r.z = __float_as_uint(buf[3 * j + 2]);
        r.w = (unsigned)(start + j);
        sbuf[slot] = r;
        sbin[slot] = (short)bin[j];
    }
    if (tid < NS) gbase[tid] = hist[tid] ? atomicAdd(&scnt[tid * CNT_STRIDE], hist[tid]) : 0;
    __syncthreads();

    int tot = pref[NS];
    float4 bias = *(const float4*)biasp;
    for (int k = tid; k < tot; k += 256) {
        int b = sbin[k];
        int dst = gbase[b] + (k - pref[b]);
        uint4 r = sbuf[k];
        if (dst < SCAP) {
            srecs[(size_t)b * SCAP + dst] = r;   // coalesced ~880B runs
        } else {
            out[r.w] = sample_one(__uint_as_float(r.x), __uint_as_float(r.y),
                                  __uint_as_float(r.z), vox, bias);
        }
    }
}

// ---------------- pass B: per stripe, bin by y-tile, coalesced write -------
__global__ __launch_bounds__(256) void binB_kernel(
    const int* __restrict__ scnt, const uint4* __restrict__ srecs,
    int* __restrict__ tcnt, uint4* __restrict__ trecs,
    const float* __restrict__ vox, const float* __restrict__ biasp,
    float4* __restrict__ out)
{
    __shared__ int hist[NTY], pref[NTY + 1], gbase[NTY];
    __shared__ uint4 sbuf[256 * PPT];
    __shared__ short sbin[256 * PPT];
    int tid = threadIdx.x;
    int s = blockIdx.x / BPS, blk = blockIdx.x % BPS;
    int cnt = min(scnt[s * CNT_STRIDE], SCAP);
    int base = blk * 256 * PPT;
    if (tid < NTY) hist[tid] = 0;
    __syncthreads();

    uint4 R[PPT];
    int bin[PPT], rank[PPT];
#pragma unroll
    for (int j = 0; j < PPT; ++j) {
        bin[j] = -1;
        int ridx = base + j * 256 + tid;         // coalesced 1KB/wave
        if (ridx < cnt) {
            R[j] = srecs[(size_t)s * SCAP + ridx];
            float py = __uint_as_float(R[j].y);
            float iyf = fminf(fmaxf(fmaf(py, 128.0f, 127.5f), 0.0f), 255.0f);
            int yt = ((int)floorf(iyf)) / YR;
            bin[j] = yt;
            rank[j] = atomicAdd(&hist[yt], 1);
        }
    }
    __syncthreads();
    if (tid == 0) {
        int t = 0;
#pragma unroll
        for (int b = 0; b < NTY; ++b) { pref[b] = t; t += hist[b]; }
        pref[NTY] = t;
    }
    __syncthreads();
#pragma unroll
    for (int j = 0; j < PPT; ++j) {
        if (bin[j] < 0) continue;
        int slot = pref[bin[j]] + rank[j];
        sbuf[slot] = R[j];
        sbin[slot] = (short)bin[j];
    }
    if (tid < NTY)
        gbase[tid] = hist[tid]
            ? atomicAdd(&tcnt[(s * NTY + tid) * CNT_STRIDE], hist[tid]) : 0;
    __syncthreads();

    int tot = pref[NTY];
    float4 bias = *(const float4*)biasp;
    for (int k = tid; k < tot; k += 256) {
        int b = sbin[k];
        int dst = gbase[b] + (k - pref[b]);
        uint4 r = sbuf[k];
        if (dst < TCAP) {
            trecs[(size_t)(s * NTY + b) * TCAP + dst] = r;
        } else {
            out[r.w] = sample_one(__uint_as_float(r.x), __uint_as_float(r.y),
                                  __uint_as_float(r.z), vox, bias);
        }
    }
}

// ---------------- sample pass: 128 KB fp16 tile per block ------------------
__global__ __launch_bounds__(1024) void sample_tiles_kernel(
    const uint4* __restrict__ trecs, const int* __restrict__ tcnt,
    const float* __restrict__ vox, const float* __restrict__ biasp,
    float4* __restrict__ out)
{
    __shared__ _Float16 tile[8 * 8 * 256 * 4];  // 128 KiB

    float4 bias = *(const float4*)biasp;
    int tid = threadIdx.x;

    for (int t = blockIdx.x; t < NTILES; t += gridDim.x) {
        int zt = t / NTY, yt = t - zt * NTY;
        int zbase = zt * ZR, ybase = yt * YR;

#pragma unroll
        for (int it = 0; it < 8; ++it) {
            int q = it * 1024 + tid;        // 0..8191
            int p = q & 127;                // x-pair index
            int rowp = q >> 7;              // 0..63
            int r = rowp & 7, pl = rowp >> 3;
            int zp = min(zbase + pl, SIDE - 1);
            int yp = min(ybase + r, SIDE - 1);
            size_t gbase = ((size_t)(zp * SIDE + yp)) * SIDE + p * 2;
            float2 f0 = *(const float2*)(vox + gbase);
            float2 f1 = *(const float2*)(vox + CHAN_STRIDE + gbase);
            float2 f2 = *(const float2*)(vox + 2 * CHAN_STRIDE + gbase);
            float2 f3 = *(const float2*)(vox + 3 * CHAN_STRIDE + gbase);
            h8_al o;
            o[0] = (_Float16)f0.x; o[1] = (_Float16)f1.x;
            o[2] = (_Float16)f2.x; o[3] = (_Float16)f3.x;
            o[4] = (_Float16)f0.y; o[5] = (_Float16)f1.y;
            o[6] = (_Float16)f2.y; o[7] = (_Float16)f3.y;
            *(h8_al*)(tile + ((size_t)rowp * 256 + p * 2) * 4) = o;
        }
        __syncthreads();

        int cnt = min(tcnt[t * CNT_STRIDE], TCAP);
        const uint4* rec = trecs + (size_t)t * TCAP;
        for (int r = tid; r < cnt; r += 1024) {
            uint4 R = rec[r];
            float px = __uint_as_float(R.x);
            float py = __uint_as_float(R.y);
            float pz = __uint_as_float(R.z);

            float ix = fminf(fmaxf(fmaf(px, 128.0f, 127.5f), 0.0f), 255.0f);
            float iy = fminf(fmaxf(fmaf(py, 128.0f, 127.5f), 0.0f), 255.0f);
            float iz = fminf(fmaxf(fmaf(pz, 128.0f, 127.5f), 0.0f), 255.0f);
            float fx = floorf(ix), fy = floorf(iy), fz = floorf(iz);
            float wx = ix - fx, wy = iy - fy, wz = iz - fz;
            int x0 = (int)fx, y0 = (int)fy, z0 = (int)fz;
            int xb = min(x0, SIDE - 2);
            bool xhi = (x0 > xb);
            int y1 = min(y0 + 1, SIDE - 1);
            int z1 = min(z0 + 1, SIDE - 1);

            int zl = z0 - zbase, zl1 = z1 - zbase;
            int yl = y0 - ybase, yl1 = y1 - ybase;

            float ux = 1.0f - wx, uy = 1.0f - wy, uz = 1.0f - wz;
            float w00 = uz * uy, w01 = uz * wy, w10 = wz * uy, w11 = wz * wy;

            h8_lds v00 = *(const h8_lds*)(tile + ((zl  * 8 + yl ) * 256 + xb) * 4);
            h8_lds v01 = *(const h8_lds*)(tile + ((zl  * 8 + yl1) * 256 + xb) * 4);
            h8_lds v10 = *(const h8_lds*)(tile + ((zl1 * 8 + yl ) * 256 + xb) * 4);
            h8_lds v11 = *(const h8_lds*)(tile + ((zl1 * 8 + yl1) * 256 + xb) * 4);

            float acc[4];
#pragma unroll
            for (int c = 0; c < 4; ++c) {
                float lo00 = (float)(xhi ? v00[4 + c] : v00[c]);
                float lo01 = (float)(xhi ? v01[4 + c] : v01[c]);
                float lo10 = (float)(xhi ? v10[4 + c] : v10[c]);
                float lo11 = (float)(xhi ? v11[4 + c] : v11[c]);
                float hi00 = (float)v00[4 + c];
                float hi01 = (float)v01[4 + c];
                float hi10 = (float)v10[4 + c];
                float hi11 = (float)v11[4 + c];
                acc[c] = w00 * fmaf(lo00, ux, hi00 * wx)
                       + w01 * fmaf(lo01, ux, hi01 * wx)
                       + w10 * fmaf(lo10, ux, hi10 * wx)
                       + w11 * fmaf(lo11, ux, hi11 * wx);
            }
            out[R.w] = make_float4(acc[0] + bias.x, acc[1] + bias.y,
                                   acc[2] + bias.z, acc[3] + bias.w);
        }
        __syncthreads();
    }
}

// ---------------- fallback: direct (R1, 636 us) ----------------------------
__global__ __launch_bounds__(256) void vox_trilerp_kernel(
    const float* __restrict__ pos, const float* __restrict__ vox,
    const float* __restrict__ biasp, float* __restrict__ out, int n)
{
    int i = blockIdx.x * blockDim.x + threadIdx.x;
    if (i >= n) return;
    float4 bias = *(const float4*)biasp;
    float4 res = sample_one(pos[3 * (size_t)i], pos[3 * (size_t)i + 1],
                            pos[3 * (size_t)i + 2], vox, bias);
    *(float4*)(out + 4 * (size_t)i) = res;
}

extern "C" void kernel_launch(void* const* d_in, const int* in_sizes, int n_in,
                              void* d_out, int out_size, void* d_ws, size_t ws_size,
                              hipStream_t stream) {
    const float* pos  = (const float*)d_in[0];
    const float* vox  = (const float*)d_in[1];
    const float* bias = (const float*)d_in[2];
    float* out = (float*)d_out;

    int n = in_sizes[0] / 3;

    if (ws_size >= WS_NEED && n >= 256 * PPT) {
        int* scnt    = (int*)((char*)d_ws + SCNT_OFF);
        int* tcnt    = (int*)((char*)d_ws + TCNT_OFF);
        uint4* srecs = (uint4*)((char*)d_ws + SRECS_OFF);
        uint4* trecs = (uint4*)((char*)d_ws + TRECS_OFF);
        hipMemsetAsync(d_ws, 0, CNT_REGION, stream);
        int grid1 = (n + 256 * PPT - 1) / (256 * PPT);
        binA_kernel<<<grid1, 256, 0, stream>>>(pos, n, scnt, srecs, vox, bias,
                                               (float4*)out);
        binB_kernel<<<NS * BPS, 256, 0, stream>>>(scnt, srecs, tcnt, trecs,
                                                  vox, bias, (float4*)out);
        sample_tiles_kernel<<<NTILES, 1024, 0, stream>>>(trecs, tcnt, vox, bias,
                                                         (float4*)out);
    } else {
        int grid = (n + 255) / 256;
        vox_trilerp_kernel<<<grid, 256, 0, stream>>>(pos, vox, bias, out, n);
    }
}

// Round 15
// 135.552 us; speedup vs baseline: 1.3419x; 1.1003x over previous
//
#include <hip/hip_runtime.h>

// 3D trilinear grid_sample (border, align_corners=False) of (4,256,256,256) f32
// voxels at N points, + bias. Output (N,4) f32.
//
// R15 = R11/R14 (149 us; 2-pass LDS-reorder radix binning + 128KB fp16
// tile-and-stage sampling) with 8-BYTE QUANTIZED RECORDS instead of 16 B:
//   w0 = qx(16b, x*256) | qy(16b) ;  w1 = qz_rel(11b) | idx(21b)
// Coords quantized to 8.8 fixed point -> output perturbation ~3e-4 (trilerp
// is continuous in the coord), invisible vs the 0.0625 fp16-table error.
// All bin/index math becomes integer fields (y-tile = (w0>>24)/7, x0=qx>>8,
// wx=(qx&255)/256): bin membership consistent by construction, sample loses
// its floorf/fmaf chains. Record traffic 132 -> 66 MB. Schedule untouched
// (ledger R7-R13: every overlap/geometry restructuring regressed).

#define SIDE 256
#define CHAN_STRIDE ((size_t)SIDE * SIDE * SIDE)
#define ZR 7
#define YR 7
#define NS 37                       // z-stripes
#define NTY 37                      // y-tiles per stripe
#define NTILES (NS * NTY)           // 1369
#define CNT_STRIDE 16               // ints -> 64 B per counter
#define PPT 8                       // points per thread in bin passes
#define SCAP 65536                  // stripe cap (border mean 58.6K)
#define TCAP 3072                   // tile cap (border mean ~1740)
#define BPS 32                      // pass-B blocks per stripe (32*2048)

// ws layout (records now 8 B)
#define SCNT_OFF 0
#define TCNT_OFF 4096
#define CNT_REGION 98304            // scnt + tcnt, zeroed each call
#define SRECS_OFF CNT_REGION
#define SRECS_BYTES ((size_t)NS * SCAP * 8)
#define TRECS_OFF (SRECS_OFF + SRECS_BYTES)
#define TRECS_BYTES ((size_t)NTILES * TCAP * 8)
#define WS_NEED (TRECS_OFF + TRECS_BYTES)   // ~53 MB

typedef float f2_unal __attribute__((ext_vector_type(2), aligned(4)));
typedef _Float16 h8_lds __attribute__((ext_vector_type(8), aligned(8)));
typedef _Float16 h8_al  __attribute__((ext_vector_type(8), aligned(16)));

// ---------------- f32 global sampling from exact pos (R1, proven) ----------
__device__ __forceinline__ float4 sample_one(
    float px, float py, float pz,
    const float* __restrict__ vox, float4 bias)
{
    float ix = fminf(fmaxf(fmaf(px, 128.0f, 127.5f), 0.0f), 255.0f);
    float iy = fminf(fmaxf(fmaf(py, 128.0f, 127.5f), 0.0f), 255.0f);
    float iz = fminf(fmaxf(fmaf(pz, 128.0f, 127.5f), 0.0f), 255.0f);
    float fx = floorf(ix), fy = floorf(iy), fz = floorf(iz);
    float wx = ix - fx, wy = iy - fy, wz = iz - fz;
    int x0 = (int)fx, y0 = (int)fy, z0 = (int)fz;
    int xb = min(x0, SIDE - 2);
    bool xhi = (x0 > xb);
    int y1 = min(y0 + 1, SIDE - 1);
    int z1 = min(z0 + 1, SIDE - 1);
    float ux = 1.0f - wx, uy = 1.0f - wy, uz = 1.0f - wz;
    float w00 = uz * uy, w01 = uz * wy, w10 = wz * uy, w11 = wz * wy;
    size_t b00 = ((size_t)(z0 * SIDE + y0)) * SIDE + xb;
    size_t b01 = ((size_t)(z0 * SIDE + y1)) * SIDE + xb;
    size_t b10 = ((size_t)(z1 * SIDE + y0)) * SIDE + xb;
    size_t b11 = ((size_t)(z1 * SIDE + y1)) * SIDE + xb;
    float r[4];
#pragma unroll
    for (int c = 0; c < 4; ++c) {
        const float* v = vox + (size_t)c * CHAN_STRIDE;
        f2_unal q00 = *(const f2_unal*)(v + b00);
        f2_unal q01 = *(const f2_unal*)(v + b01);
        f2_unal q10 = *(const f2_unal*)(v + b10);
        f2_unal q11 = *(const f2_unal*)(v + b11);
        float a00 = xhi ? q00.y : q00.x;
        float a01 = xhi ? q01.y : q01.x;
        float a10 = xhi ? q10.y : q10.x;
        float a11 = xhi ? q11.y : q11.x;
        r[c] = w00 * fmaf(a00, ux, q00.y * wx)
             + w01 * fmaf(a01, ux, q01.y * wx)
             + w10 * fmaf(a10, ux, q10.y * wx)
             + w11 * fmaf(a11, ux, q11.y * wx);
    }
    return make_float4(r[0] + bias.x, r[1] + bias.y, r[2] + bias.z, r[3] + bias.w);
}

// ---------------- f32 global sampling from quantized coords ---------------
__device__ __forceinline__ float4 sample_one_q(
    unsigned qx, unsigned qy, unsigned qza,
    const float* __restrict__ vox, float4 bias)
{
    int x0 = qx >> 8, y0 = qy >> 8, z0 = qza >> 8;
    float wx = (float)(qx & 255) * 0.00390625f;
    float wy = (float)(qy & 255) * 0.00390625f;
    float wz = (float)(qza & 255) * 0.00390625f;
    int xb = min(x0, SIDE - 2);
    bool xhi = (x0 > xb);
    int y1 = min(y0 + 1, SIDE - 1);
    int z1 = min(z0 + 1, SIDE - 1);
    float ux = 1.0f - wx, uy = 1.0f - wy, uz = 1.0f - wz;
    float w00 = uz * uy, w01 = uz * wy, w10 = wz * uy, w11 = wz * wy;
    size_t b00 = ((size_t)(z0 * SIDE + y0)) * SIDE + xb;
    size_t b01 = ((size_t)(z0 * SIDE + y1)) * SIDE + xb;
    size_t b10 = ((size_t)(z1 * SIDE + y0)) * SIDE + xb;
    size_t b11 = ((size_t)(z1 * SIDE + y1)) * SIDE + xb;
    float r[4];
#pragma unroll
    for (int c = 0; c < 4; ++c) {
        const float* v = vox + (size_t)c * CHAN_STRIDE;
        f2_unal q00 = *(const f2_unal*)(v + b00);
        f2_unal q01 = *(const f2_unal*)(v + b01);
        f2_unal q10 = *(const f2_unal*)(v + b10);
        f2_unal q11 = *(const f2_unal*)(v + b11);
        float a00 = xhi ? q00.y : q00.x;
        float a01 = xhi ? q01.y : q01.x;
        float a10 = xhi ? q10.y : q10.x;
        float a11 = xhi ? q11.y : q11.x;
        r[c] = w00 * fmaf(a00, ux, q00.y * wx)
             + w01 * fmaf(a01, ux, q01.y * wx)
             + w10 * fmaf(a10, ux, q10.y * wx)
             + w11 * fmaf(a11, ux, q11.y * wx);
    }
    return make_float4(r[0] + bias.x, r[1] + bias.y, r[2] + bias.z, r[3] + bias.w);
}

// ---------------- pass A: quantize, bin by z-stripe, LDS reorder -----------
__global__ __launch_bounds__(256) void binA_kernel(
    const float* __restrict__ pos, int n,
    int* __restrict__ scnt, uint2* __restrict__ srecs,
    const float* __restrict__ vox, const float* __restrict__ biasp,
    float4* __restrict__ out)
{
    __shared__ int hist[NS], pref[NS + 1], gbase[NS];
    __shared__ uint2 sbuf[256 * PPT];
    __shared__ short sbin[256 * PPT];
    int tid = threadIdx.x;
    if (tid < NS) hist[tid] = 0;
    __syncthreads();

    size_t start = ((size_t)blockIdx.x * 256 + tid) * PPT;
    float buf[3 * PPT];
    bool full = (start + PPT <= (size_t)n);
    if (full) {
        const float4* p4 = (const float4*)(pos + 3 * start);
#pragma unroll
        for (int k = 0; k < 3 * PPT / 4; ++k) ((float4*)buf)[k] = p4[k];
    } else {
#pragma unroll
        for (int k = 0; k < 3 * PPT; ++k) {
            size_t e = 3 * start + k;
            buf[k] = (e < 3 * (size_t)n) ? pos[e] : 0.0f;
        }
    }

    int bin[PPT], rank[PPT];
    uint2 recs_r[PPT];
#pragma unroll
    for (int j = 0; j < PPT; ++j) {
        bin[j] = -1;
        if (start + j < (size_t)n) {
            float ixf = fminf(fmaxf(fmaf(buf[3 * j + 0], 128.0f, 127.5f), 0.0f), 255.0f);
            float iyf = fminf(fmaxf(fmaf(buf[3 * j + 1], 128.0f, 127.5f), 0.0f), 255.0f);
            float izf = fminf(fmaxf(fmaf(buf[3 * j + 2], 128.0f, 127.5f), 0.0f), 255.0f);
            unsigned qx  = (unsigned)(ixf * 256.0f + 0.5f);   // <= 65280
            unsigned qy  = (unsigned)(iyf * 256.0f + 0.5f);
            unsigned qza = (unsigned)(izf * 256.0f + 0.5f);
            int zs = (int)(qza >> 8) / ZR;                    // stripe, consistent
            unsigned qzr = qza - (unsigned)(zs * (ZR << 8));  // < 1792 (11 bits)
            recs_r[j].x = qx | (qy << 16);
            recs_r[j].y = qzr | ((unsigned)(start + j) << 11);
            bin[j] = zs;
            rank[j] = atomicAdd(&hist[zs], 1);
        }
    }
    __syncthreads();
    if (tid == 0) {
        int s = 0;
#pragma unroll
        for (int b = 0; b < NS; ++b) { pref[b] = s; s += hist[b]; }
        pref[NS] = s;
    }
    __syncthreads();
#pragma unroll
    for (int j = 0; j < PPT; ++j) {
        if (bin[j] < 0) continue;
        int slot = pref[bin[j]] + rank[j];
        sbuf[slot] = recs_r[j];
        sbin[slot] = (short)bin[j];
    }
    if (tid < NS) gbase[tid] = hist[tid] ? atomicAdd(&scnt[tid * CNT_STRIDE], hist[tid]) : 0;
    __syncthreads();

    int tot = pref[NS];
    float4 bias = *(const float4*)biasp;
    for (int k = tid; k < tot; k += 256) {
        int b = sbin[k];
        int dst = gbase[b] + (k - pref[b]);
        uint2 r = sbuf[k];
        if (dst < SCAP) {
            srecs[(size_t)b * SCAP + dst] = r;   // coalesced runs
        } else {
            unsigned qx = r.x & 0xFFFFu, qy = r.x >> 16;
            unsigned qza = (r.y & 0x7FFu) + (unsigned)(b * (ZR << 8));
            out[r.y >> 11] = sample_one_q(qx, qy, qza, vox, bias);
        }
    }
}

// ---------------- pass B: per stripe, bin by y-tile, coalesced write -------
__global__ __launch_bounds__(256) void binB_kernel(
    const int* __restrict__ scnt, const uint2* __restrict__ srecs,
    int* __restrict__ tcnt, uint2* __restrict__ trecs,
    const float* __restrict__ vox, const float* __restrict__ biasp,
    float4* __restrict__ out)
{
    __shared__ int hist[NTY], pref[NTY + 1], gbase[NTY];
    __shared__ uint2 sbuf[256 * PPT];
    __shared__ short sbin[256 * PPT];
    int tid = threadIdx.x;
    int s = blockIdx.x / BPS, blk = blockIdx.x % BPS;
    int cnt = min(scnt[s * CNT_STRIDE], SCAP);
    int base = blk * 256 * PPT;
    if (tid < NTY) hist[tid] = 0;
    __syncthreads();

    uint2 R[PPT];
    int bin[PPT], rank[PPT];
#pragma unroll
    for (int j = 0; j < PPT; ++j) {
        bin[j] = -1;
        int ridx = base + j * 256 + tid;         // coalesced
        if (ridx < cnt) {
            R[j] = srecs[(size_t)s * SCAP + ridx];
            int yt = (int)(R[j].x >> 24) / YR;   // y0q = top 8 bits
            bin[j] = yt;
            rank[j] = atomicAdd(&hist[yt], 1);
        }
    }
    __syncthreads();
    if (tid == 0) {
        int t = 0;
#pragma unroll
        for (int b = 0; b < NTY; ++b) { pref[b] = t; t += hist[b]; }
        pref[NTY] = t;
    }
    __syncthreads();
#pragma unroll
    for (int j = 0; j < PPT; ++j) {
        if (bin[j] < 0) continue;
        int slot = pref[bin[j]] + rank[j];
        sbuf[slot] = R[j];
        sbin[slot] = (short)bin[j];
    }
    if (tid < NTY)
        gbase[tid] = hist[tid]
            ? atomicAdd(&tcnt[(s * NTY + tid) * CNT_STRIDE], hist[tid]) : 0;
    __syncthreads();

    int tot = pref[NTY];
    float4 bias = *(const float4*)biasp;
    for (int k = tid; k < tot; k += 256) {
        int b = sbin[k];
        int dst = gbase[b] + (k - pref[b]);
        uint2 r = sbuf[k];
        if (dst < TCAP) {
            trecs[(size_t)(s * NTY + b) * TCAP + dst] = r;
        } else {
            unsigned qx = r.x & 0xFFFFu, qy = r.x >> 16;
            unsigned qza = (r.y & 0x7FFu) + (unsigned)(s * (ZR << 8));
            out[r.y >> 11] = sample_one_q(qx, qy, qza, vox, bias);
        }
    }
}

// ---------------- sample pass: 128 KB fp16 tile per block ------------------
__global__ __launch_bounds__(1024) void sample_tiles_kernel(
    const uint2* __restrict__ trecs, const int* __restrict__ tcnt,
    const float* __restrict__ vox, const float* __restrict__ biasp,
    float4* __restrict__ out)
{
    __shared__ _Float16 tile[8 * 8 * 256 * 4];  // 128 KiB

    float4 bias = *(const float4*)biasp;
    int tid = threadIdx.x;

    for (int t = blockIdx.x; t < NTILES; t += gridDim.x) {
        int zt = t / NTY, yt = t - zt * NTY;
        int zbase = zt * ZR, ybase = yt * YR;

#pragma unroll
        for (int it = 0; it < 8; ++it) {
            int q = it * 1024 + tid;        // 0..8191
            int p = q & 127;                // x-pair index
            int rowp = q >> 7;              // 0..63
            int r = rowp & 7, pl = rowp >> 3;
            int zp = min(zbase + pl, SIDE - 1);
            int yp = min(ybase + r, SIDE - 1);
            size_t gbase = ((size_t)(zp * SIDE + yp)) * SIDE + p * 2;
            float2 f0 = *(const float2*)(vox + gbase);
            float2 f1 = *(const float2*)(vox + CHAN_STRIDE + gbase);
            float2 f2 = *(const float2*)(vox + 2 * CHAN_STRIDE + gbase);
            float2 f3 = *(const float2*)(vox + 3 * CHAN_STRIDE + gbase);
            h8_al o;
            o[0] = (_Float16)f0.x; o[1] = (_Float16)f1.x;
            o[2] = (_Float16)f2.x; o[3] = (_Float16)f3.x;
            o[4] = (_Float16)f0.y; o[5] = (_Float16)f1.y;
            o[6] = (_Float16)f2.y; o[7] = (_Float16)f3.y;
            *(h8_al*)(tile + ((size_t)rowp * 256 + p * 2) * 4) = o;
        }
        __syncthreads();

        int cnt = min(tcnt[t * CNT_STRIDE], TCAP);
        const uint2* rec = trecs + (size_t)t * TCAP;
        for (int r = tid; r < cnt; r += 1024) {
            uint2 R = rec[r];
            unsigned qx = R.x & 0xFFFFu, qy = R.x >> 16;
            unsigned qzr = R.y & 0x7FFu;
            unsigned idx = R.y >> 11;

            int x0 = qx >> 8;
            int xb = min(x0, SIDE - 2);
            bool xhi = (x0 > xb);
            int yl = (int)(qy >> 8) - ybase;   // 0..6 (tile membership exact)
            int zl = qzr >> 8;                 // 0..6
            // zl+1 / yl+1 rows are staged with border duplication -> clamp free
            float wx = (float)(qx & 255) * 0.00390625f;
            float wy = (float)(qy & 255) * 0.00390625f;
            float wz = (float)(qzr & 255) * 0.00390625f;

            float ux = 1.0f - wx, uy = 1.0f - wy, uz = 1.0f - wz;
            float w00 = uz * uy, w01 = uz * wy, w10 = wz * uy, w11 = wz * wy;

            int r00 = zl * 8 + yl;
            h8_lds v00 = *(const h8_lds*)(tile + ((r00    ) * 256 + xb) * 4);
            h8_lds v01 = *(const h8_lds*)(tile + ((r00 + 1) * 256 + xb) * 4);
            h8_lds v10 = *(const h8_lds*)(tile + ((r00 + 8) * 256 + xb) * 4);
            h8_lds v11 = *(const h8_lds*)(tile + ((r00 + 9) * 256 + xb) * 4);

            float acc[4];
#pragma unroll
            for (int c = 0; c < 4; ++c) {
                float lo00 = (float)(xhi ? v00[4 + c] : v00[c]);
                float lo01 = (float)(xhi ? v01[4 + c] : v01[c]);
                float lo10 = (float)(xhi ? v10[4 + c] : v10[c]);
                float lo11 = (float)(xhi ? v11[4 + c] : v11[c]);
                float hi00 = (float)v00[4 + c];
                float hi01 = (float)v01[4 + c];
                float hi10 = (float)v10[4 + c];
                float hi11 = (float)v11[4 + c];
                acc[c] = w00 * fmaf(lo00, ux, hi00 * wx)
                       + w01 * fmaf(lo01, ux, hi01 * wx)
                       + w10 * fmaf(lo10, ux, hi10 * wx)
                       + w11 * fmaf(lo11, ux, hi11 * wx);
            }
            out[idx] = make_float4(acc[0] + bias.x, acc[1] + bias.y,
                                   acc[2] + bias.z, acc[3] + bias.w);
        }
        __syncthreads();
    }
}

// ---------------- fallback: direct (R1, 636 us) ----------------------------
__global__ __launch_bounds__(256) void vox_trilerp_kernel(
    const float* __restrict__ pos, const float* __restrict__ vox,
    const float* __restrict__ biasp, float* __restrict__ out, int n)
{
    int i = blockIdx.x * blockDim.x + threadIdx.x;
    if (i >= n) return;
    float4 bias = *(const float4*)biasp;
    float4 res = sample_one(pos[3 * (size_t)i], pos[3 * (size_t)i + 1],
                            pos[3 * (size_t)i + 2], vox, bias);
    *(float4*)(out + 4 * (size_t)i) = res;
}

extern "C" void kernel_launch(void* const* d_in, const int* in_sizes, int n_in,
                              void* d_out, int out_size, void* d_ws, size_t ws_size,
                              hipStream_t stream) {
    const float* pos  = (const float*)d_in[0];
    const float* vox  = (const float*)d_in[1];
    const float* bias = (const float*)d_in[2];
    float* out = (float*)d_out;

    int n = in_sizes[0] / 3;

    // idx field is 21 bits -> binned path requires n <= 2^21
    if (ws_size >= WS_NEED && n >= 256 * PPT && n <= (1 << 21)) {
        int* scnt    = (int*)((char*)d_ws + SCNT_OFF);
        int* tcnt    = (int*)((char*)d_ws + TCNT_OFF);
        uint2* srecs = (uint2*)((char*)d_ws + SRECS_OFF);
        uint2* trecs = (uint2*)((char*)d_ws + TRECS_OFF);
        hipMemsetAsync(d_ws, 0, CNT_REGION, stream);
        int grid1 = (n + 256 * PPT - 1) / (256 * PPT);
        binA_kernel<<<grid1, 256, 0, stream>>>(pos, n, scnt, srecs, vox, bias,
                                               (float4*)out);
        binB_kernel<<<NS * BPS, 256, 0, stream>>>(scnt, srecs, tcnt, trecs,
                                                  vox, bias, (float4*)out);
        sample_tiles_kernel<<<NTILES, 1024, 0, stream>>>(trecs, tcnt, vox, bias,
                                                         (float4*)out);
    } else {
        int grid = (n + 255) / 256;
        vox_trilerp_kernel<<<grid, 256, 0, stream>>>(pos, vox, bias, out, n);
    }
}